// Round 15
// baseline (345.943 us; speedup 1.0000x reference)
//
#include <hip/hip_runtime.h>
#include <hip/hip_bf16.h>

#define C 64
#define H 128
#define FEPS 1e-7f
#define BNE 1e-5f
#define BSH 9
#define BSZ 512   // nodes per bucket
#define EPB 4096  // edges per block in bhist/bscat

typedef __attribute__((ext_vector_type(8))) short bf16x8;
typedef __attribute__((ext_vector_type(4))) float f32x4;

__device__ __forceinline__ float us2f(ushort u) {
    unsigned int x = ((unsigned int)u) << 16;
    return __uint_as_float(x);
}
__device__ __forceinline__ ushort f2us(float f) {
    __hip_bfloat16 h = __float2bfloat16(f);
    return *reinterpret_cast<ushort*>(&h);
}

// ---------------- CSR build (bucketed; packed (loc,src) scatter word) ----------------
__global__ __launch_bounds__(256) void bhist_k(const int* __restrict__ dst,
                                               int* __restrict__ bucket_cnt, int E, int NB) {
    __shared__ int cnt[256];
    int tid = threadIdx.x;
    cnt[tid] = 0;
    __syncthreads();
    int base = blockIdx.x * EPB;
#pragma unroll
    for (int j = 0; j < 16; j++) {
        int e = base + tid + j * 256;
        if (e < E) atomicAdd(&cnt[dst[e] >> BSH], 1);
    }
    __syncthreads();
    if (tid < NB && cnt[tid]) atomicAdd(&bucket_cnt[tid], cnt[tid]);
}

__global__ void bscan_k(const int* __restrict__ bucket_cnt, int* __restrict__ bucket_off,
                        int* __restrict__ bucket_fill, int* __restrict__ row_start,
                        int NB, int N, int E) {
    __shared__ int s[256];
    int tid = threadIdx.x;
    int v = (tid < NB) ? bucket_cnt[tid] : 0;
    s[tid] = v;
    __syncthreads();
    for (int off = 1; off < 256; off <<= 1) {
        int t = 0;
        if (tid >= off) t = s[tid - off];
        __syncthreads();
        s[tid] += t;
        __syncthreads();
    }
    int excl = s[tid] - v;
    if (tid < NB) { bucket_off[tid] = excl; bucket_fill[tid] = excl; }
    if (tid == NB - 1) bucket_off[NB] = s[tid];
    if (tid == 0) row_start[N] = E;
}

// packed word: (dst & (BSZ-1)) << 17 | src   (requires N < 2^17 = 131072)
__global__ __launch_bounds__(256) void bscat_k(const int* __restrict__ src,
                                               const int* __restrict__ dst,
                                               int* __restrict__ bucket_fill,
                                               unsigned int* __restrict__ bpak, int E) {
    __shared__ int cnt[256];
    __shared__ int sbase[256];
    int tid = threadIdx.x;
    cnt[tid] = 0;
    __syncthreads();
    int base = blockIdx.x * EPB;
    int dd[16], rk[16];
#pragma unroll
    for (int j = 0; j < 16; j++) {
        int e = base + tid + j * 256;
        dd[j] = -1;
        if (e < E) {
            int d = dst[e];
            dd[j] = d;
            rk[j] = atomicAdd(&cnt[d >> BSH], 1);
        }
    }
    __syncthreads();
    if (cnt[tid]) sbase[tid] = atomicAdd(&bucket_fill[tid], cnt[tid]);
    __syncthreads();
#pragma unroll
    for (int j = 0; j < 16; j++) {
        if (dd[j] >= 0) {
            int e = base + tid + j * 256;
            int b = dd[j] >> BSH;
            int pos = sbase[b] + rk[j];
            bpak[pos] = ((unsigned int)(dd[j] & (BSZ - 1)) << 17) | (unsigned int)src[e];
        }
    }
}

__global__ __launch_bounds__(512) void bfine_k(const int* __restrict__ bucket_off,
                                               const unsigned int* __restrict__ bpak,
                                               int* __restrict__ row_start,
                                               int* __restrict__ col, int N) {
    __shared__ int cnt[BSZ];
    __shared__ int off[BSZ];
    __shared__ int fill[BSZ];
    int tid = threadIdx.x;
    int b = blockIdx.x;
    int e0 = bucket_off[b], e1 = bucket_off[b + 1];
    int nbase = b << BSH;
    cnt[tid] = 0; fill[tid] = 0;
    __syncthreads();
    for (int e = e0 + tid; e < e1; e += 512) atomicAdd(&cnt[bpak[e] >> 17], 1);
    __syncthreads();
    int v = cnt[tid];
    off[tid] = v;
    __syncthreads();
    for (int o = 1; o < 512; o <<= 1) {
        int t = 0;
        if (tid >= o) t = off[tid - o];
        __syncthreads();
        off[tid] += t;
        __syncthreads();
    }
    int excl = off[tid] - v;
    off[tid] = excl;
    __syncthreads();
    int n = nbase + tid;
    if (n < N) row_start[n] = e0 + excl;
    for (int e = e0 + tid; e < e1; e += 512) {
        unsigned int w = bpak[e];
        int loc = w >> 17;
        int r = atomicAdd(&fill[loc], 1);
        col[e0 + off[loc] + r] = (int)(w & 0x1FFFFu);
    }
}

// ---------------- degree-sorted node permutation (counting sort, 64 bins) ----------------
__global__ __launch_bounds__(256) void dhist_k(const int* __restrict__ rs,
                                               int* __restrict__ dbin, int N) {
    __shared__ int h[64];
    int tid = threadIdx.x;
    if (tid < 64) h[tid] = 0;
    __syncthreads();
#pragma unroll
    for (int j = 0; j < 4; j++) {
        int i = blockIdx.x * 1024 + tid + j * 256;
        if (i < N) {
            int deg = rs[i + 1] - rs[i];
            atomicAdd(&h[min(deg, 63)], 1);
        }
    }
    __syncthreads();
    if (tid < 64 && h[tid]) atomicAdd(&dbin[tid], h[tid]);
}

__global__ void dscan_k(const int* __restrict__ dbin, int* __restrict__ dbfill) {
    __shared__ int s[64];
    int tid = threadIdx.x;   // 64 threads
    int v = dbin[tid];
    s[tid] = v;
    __syncthreads();
    for (int o = 1; o < 64; o <<= 1) {
        int t = 0;
        if (tid >= o) t = s[tid - o];
        __syncthreads();
        s[tid] += t;
        __syncthreads();
    }
    dbfill[tid] = s[tid] - v;
}

__global__ __launch_bounds__(256) void dscat_k(const int* __restrict__ rs,
                                               int* __restrict__ dbfill,
                                               int* __restrict__ perm, int N) {
    __shared__ int cnt[64];
    __shared__ int sb[64];
    int tid = threadIdx.x;
    if (tid < 64) cnt[tid] = 0;
    __syncthreads();
    int bn[4], rk[4];
#pragma unroll
    for (int j = 0; j < 4; j++) {
        int i = blockIdx.x * 1024 + tid + j * 256;
        bn[j] = -1;
        if (i < N) {
            int deg = rs[i + 1] - rs[i];
            bn[j] = min(deg, 63);
            rk[j] = atomicAdd(&cnt[bn[j]], 1);
        }
    }
    __syncthreads();
    if (tid < 64 && cnt[tid]) sb[tid] = atomicAdd(&dbfill[tid], cnt[tid]);
    __syncthreads();
#pragma unroll
    for (int j = 0; j < 4; j++) {
        if (bn[j] >= 0) {
            int i = blockIdx.x * 1024 + tid + j * 256;
            perm[sb[bn[j]] + rk[j]] = i;
        }
    }
}

// ---------------- message prep: marr = bf16(relu(x)+eps), x possibly BN-affined ----------------
template <int AFF>
__global__ __launch_bounds__(256) void prep_k(const float* __restrict__ in,
                                              const float* __restrict__ fa,
                                              const float* __restrict__ fc,
                                              ushort* __restrict__ marr, int total4) {
    int i = blockIdx.x * 256 + threadIdx.x;
    if (i >= total4) return;
    float4 v = ((const float4*)in)[i];
    int c0 = (i * 4) & 63;
    float vv[4] = {v.x, v.y, v.z, v.w};
    ushort u[4];
#pragma unroll
    for (int j = 0; j < 4; j++) {
        float x = vv[j];
        if (AFF) {
            float xv = fmaxf(x * fa[c0 + j] + fc[c0 + j], 0.f) + FEPS;
            x = xv + FEPS;
        } else {
            x = fmaxf(x, 0.f) + FEPS;
        }
        u[j] = f2us(x);
    }
    ushort4 uv = make_ushort4(u[0], u[1], u[2], u[3]);
    ((ushort4*)marr)[i] = uv;
}

// ---------------- fused softmax-aggregation + MessageNorm ----------------
// Quarter-per-node over degree-sorted perm; col indices prefetched one iteration
// ahead via aligned int4; 8 marr gathers in flight.
template <int MODE>
__global__ __launch_bounds__(256) void agg_k(const float* __restrict__ xin,
                                             const float* __restrict__ ta,
                                             const float* __restrict__ tc,
                                             const uint2* __restrict__ marr64,
                                             const int* __restrict__ rs,
                                             const int* __restrict__ col,
                                             const int* __restrict__ perm,
                                             const float* __restrict__ t,
                                             const float* __restrict__ sc,
                                             int layer, float* __restrict__ outb, int N) {
    int lane = threadIdx.x & 63;
    int wid = threadIdx.x >> 6;
    int q = lane >> 4;      // quarter 0..3 -> node
    int ql = lane & 15;     // owns channels 4ql..4ql+3
    int gid = blockIdx.x * 16 + wid * 4 + q;
    if (gid >= N) return;
    int n = perm[gid];
    float tv = t[layer];
    float sv = sc[layer];

    int beg = rs[n], end = rs[n + 1];
    float den[4] = {0.f, 0.f, 0.f, 0.f}, num[4] = {0.f, 0.f, 0.f, 0.f};

    auto acc4 = [&](uint2 d) {
        float m0 = __uint_as_float(d.x << 16);
        float m1 = __uint_as_float(d.x & 0xffff0000u);
        float m2 = __uint_as_float(d.y << 16);
        float m3 = __uint_as_float(d.y & 0xffff0000u);
        float e0 = __expf(m0 * tv);
        float e1 = __expf(m1 * tv);
        float e2 = __expf(m2 * tv);
        float e3 = __expf(m3 * tv);
        den[0] += e0; num[0] += m0 * e0;
        den[1] += e1; num[1] += m1 * e1;
        den[2] += e2; num[2] += m2 * e2;
        den[3] += e3; num[3] += m3 * e3;
    };

    int e = beg;
    // scalar head to 16B-align col pointer
    int head = (4 - (e & 3)) & 3;
    if (head > end - e) head = end - e;
    for (int i = 0; i < head; i++, e++) {
        uint2 d0 = marr64[(size_t)col[e] * 16 + ql];
        acc4(d0);
    }
    if (e + 8 <= end) {
        int4 ca = *(const int4*)(col + e);
        int4 cb = *(const int4*)(col + e + 4);
        while (true) {
            uint2 d0 = marr64[(size_t)ca.x * 16 + ql];
            uint2 d1 = marr64[(size_t)ca.y * 16 + ql];
            uint2 d2 = marr64[(size_t)ca.z * 16 + ql];
            uint2 d3 = marr64[(size_t)ca.w * 16 + ql];
            uint2 d4 = marr64[(size_t)cb.x * 16 + ql];
            uint2 d5 = marr64[(size_t)cb.y * 16 + ql];
            uint2 d6 = marr64[(size_t)cb.z * 16 + ql];
            uint2 d7 = marr64[(size_t)cb.w * 16 + ql];
            e += 8;
            bool more = (e + 8 <= end);
            if (more) {
                ca = *(const int4*)(col + e);
                cb = *(const int4*)(col + e + 4);
            }
            acc4(d0); acc4(d1); acc4(d2); acc4(d3);
            acc4(d4); acc4(d5); acc4(d6); acc4(d7);
            if (!more) break;
        }
    }
    for (; e < end; e++) {
        uint2 d0 = marr64[(size_t)col[e] * 16 + ql];
        acc4(d0);
    }

    float agg[4], aq = 0.f;
#pragma unroll
    for (int c = 0; c < 4; c++) {
        agg[c] = (den[c] > 0.f) ? (num[c] / den[c]) : 0.f;
        aq += agg[c] * agg[c];
    }

    float4 xv = ((const float4*)xin)[(size_t)n * 16 + ql];
    float xn[4];
    if (MODE == 0) {
        xn[0] = xv.x; xn[1] = xv.y; xn[2] = xv.z; xn[3] = xv.w;
    } else {
        float4 av = ((const float4*)ta)[ql];
        float4 cv = ((const float4*)tc)[ql];
        xn[0] = fmaxf(xv.x * av.x + cv.x, 0.f) + FEPS;
        xn[1] = fmaxf(xv.y * av.y + cv.y, 0.f) + FEPS;
        xn[2] = fmaxf(xv.z * av.z + cv.z, 0.f) + FEPS;
        xn[3] = fmaxf(xv.w * av.w + cv.w, 0.f) + FEPS;
    }
    float xq = xn[0] * xn[0] + xn[1] * xn[1] + xn[2] * xn[2] + xn[3] * xn[3];
    float na = aq, nx = xq;
#pragma unroll
    for (int m = 1; m <= 8; m <<= 1) {
        na += __shfl_xor(na, m, 64);
        nx += __shfl_xor(nx, m, 64);
    }
    float s = (1.0f / fmaxf(sqrtf(na), 1e-12f)) * sqrtf(nx) * sv;
    float4 o;
    o.x = xn[0] + agg[0] * s;
    o.y = xn[1] + agg[1] * s;
    o.z = xn[2] + agg[2] * s;
    o.w = xn[3] + agg[3] * s;
    ((float4*)outb)[(size_t)n * 16 + ql] = o;
}

// ---------------- weight pre-transpose: Wt[col][k] bf16 (once per call) ----------------
__global__ void wprep_k(const float* __restrict__ W1, const float* __restrict__ W2,
                        ushort* __restrict__ wt1, ushort* __restrict__ wt2) {
    int idx = blockIdx.x * 256 + threadIdx.x;   // 0..32767
    int m = idx >> 13, w = idx & 8191;
    if (m < 2) {
        int colw = w >> 6, k = w & 63;
        wt1[idx] = f2us(W1[m * 8192 + k * 128 + colw]);
    } else {
        int l = m - 2;
        int colw = w >> 7, k = w & 127;
        wt2[l * 8192 + w] = f2us(W2[l * 8192 + k * 64 + colw]);
    }
}

// ---------------- MFMA MLP GEMM v2: barrier-free streaming, both row-tiles prefetched ----------------
template <int KD, int ND, int MODE>
__global__ __launch_bounds__(256) void mlpm_k(const void* __restrict__ Ain,
                                              const float* __restrict__ fa,
                                              const float* __restrict__ fc,
                                              const ushort* __restrict__ WtT,
                                              const float* __restrict__ bias,
                                              void* __restrict__ outp,
                                              float* __restrict__ s_sum,
                                              float* __restrict__ s_ssq, int N) {
    constexpr int NT = ND / 16;   // col tiles
    constexpr int KS = KD / 32;   // k slices
    __shared__ float ssum[ND], sssq[ND];
    int tid = threadIdx.x;
    int wave = tid >> 6, lane = tid & 63, lrow = lane & 15, kg = lane >> 4;
    if (tid < ND) { ssum[tid] = 0.f; sssq[tid] = 0.f; }
    __syncthreads();

    int base = blockIdx.x * 128;

    bf16x8 wfr[NT][KS];
#pragma unroll
    for (int t = 0; t < NT; t++)
#pragma unroll
        for (int ks = 0; ks < KS; ks++)
            wfr[t][ks] = *(const bf16x8*)(WtT + (t * 16 + lrow) * KD + ks * 32 + kg * 8);
    float bv[NT];
#pragma unroll
    for (int t = 0; t < NT; t++) bv[t] = bias[t * 16 + lrow];

    float ls[NT], lq[NT];
#pragma unroll
    for (int t = 0; t < NT; t++) { ls[t] = 0.f; lq[t] = 0.f; }

    // ---- load BOTH row-tiles' A data before converting/computing ----
    bf16x8 afr[2][KS];
    if (MODE == 0) {
        float4 raw[2][KS][2];
#pragma unroll
        for (int rt = 0; rt < 2; rt++) {
            int arow = base + (wave * 2 + rt) * 16 + lrow;
            bool rok = arow < N;
#pragma unroll
            for (int ks = 0; ks < KS; ks++) {
                float4 z = make_float4(0.f, 0.f, 0.f, 0.f);
                raw[rt][ks][0] = z; raw[rt][ks][1] = z;
                if (rok) {
                    const float4* p = (const float4*)((const float*)Ain +
                                                      (size_t)arow * KD + ks * 32 + kg * 8);
                    raw[rt][ks][0] = p[0];
                    raw[rt][ks][1] = p[1];
                }
            }
        }
#pragma unroll
        for (int rt = 0; rt < 2; rt++)
#pragma unroll
            for (int ks = 0; ks < KS; ks++) {
                float4 v0 = raw[rt][ks][0], v1 = raw[rt][ks][1];
                bf16x8 a;
                a[0] = (short)f2us(v0.x); a[1] = (short)f2us(v0.y);
                a[2] = (short)f2us(v0.z); a[3] = (short)f2us(v0.w);
                a[4] = (short)f2us(v1.x); a[5] = (short)f2us(v1.y);
                a[6] = (short)f2us(v1.z); a[7] = (short)f2us(v1.w);
                afr[rt][ks] = a;
            }
    } else {
        uint4 raw[2][KS];
#pragma unroll
        for (int rt = 0; rt < 2; rt++) {
            int arow = base + (wave * 2 + rt) * 16 + lrow;
            bool rok = arow < N;
#pragma unroll
            for (int ks = 0; ks < KS; ks++) {
                raw[rt][ks] = make_uint4(0u, 0u, 0u, 0u);
                if (rok) raw[rt][ks] = *(const uint4*)((const ushort*)Ain +
                                                       (size_t)arow * KD + ks * 32 + kg * 8);
            }
        }
#pragma unroll
        for (int rt = 0; rt < 2; rt++)
#pragma unroll
            for (int ks = 0; ks < KS; ks++) {
                int k0 = ks * 32 + kg * 8;
                float4 a0 = *(const float4*)(fa + k0);
                float4 a1 = *(const float4*)(fa + k0 + 4);
                float4 c0 = *(const float4*)(fc + k0);
                float4 c1 = *(const float4*)(fc + k0 + 4);
                unsigned int w[4] = {raw[rt][ks].x, raw[rt][ks].y, raw[rt][ks].z, raw[rt][ks].w};
                float av[8] = {a0.x, a0.y, a0.z, a0.w, a1.x, a1.y, a1.z, a1.w};
                float cv[8] = {c0.x, c0.y, c0.z, c0.w, c1.x, c1.y, c1.z, c1.w};
                bf16x8 a;
#pragma unroll
                for (int p = 0; p < 4; p++) {
                    float f0 = us2f((ushort)(w[p] & 0xffffu));
                    float f1 = us2f((ushort)(w[p] >> 16));
                    f0 = fmaxf(f0 * av[2 * p] + cv[2 * p], 0.f);
                    f1 = fmaxf(f1 * av[2 * p + 1] + cv[2 * p + 1], 0.f);
                    a[2 * p] = (short)f2us(f0);
                    a[2 * p + 1] = (short)f2us(f1);
                }
                afr[rt][ks] = a;
            }
    }

#pragma unroll
    for (int rt = 0; rt < 2; rt++) {
        int tidx = wave * 2 + rt;
#pragma unroll
        for (int t = 0; t < NT; t++) {
            f32x4 acc = {0.f, 0.f, 0.f, 0.f};
#pragma unroll
            for (int ks = 0; ks < KS; ks++)
                acc = __builtin_amdgcn_mfma_f32_16x16x32_bf16(afr[rt][ks], wfr[t][ks], acc, 0, 0, 0);
            int colw = t * 16 + lrow;
#pragma unroll
            for (int r = 0; r < 4; r++) {
                int orow = base + tidx * 16 + kg * 4 + r;
                float v = acc[r] + bv[t];
                if (orow < N) {
                    if (MODE == 0) ((ushort*)outp)[(size_t)orow * ND + colw] = f2us(v);
                    else ((float*)outp)[(size_t)orow * ND + colw] = v;
                    ls[t] += v; lq[t] += v * v;
                }
            }
        }
    }

#pragma unroll
    for (int t = 0; t < NT; t++) {
        float a = ls[t], b = lq[t];
        a += __shfl_xor(a, 16, 64); a += __shfl_xor(a, 32, 64);
        b += __shfl_xor(b, 16, 64); b += __shfl_xor(b, 32, 64);
        if (kg == 0) {
            atomicAdd(&ssum[t * 16 + lrow], a);
            atomicAdd(&sssq[t * 16 + lrow], b);
        }
    }
    __syncthreads();
    if (tid < ND) {
        atomicAdd(&s_sum[tid], ssum[tid]);
        atomicAdd(&s_ssq[tid], sssq[tid]);
    }
}

// ---------------- BN finalize ----------------
__global__ void bnfin_k(const float* __restrict__ sum, const float* __restrict__ ssq,
                        const float* __restrict__ g, const float* __restrict__ b,
                        float* __restrict__ a, float* __restrict__ cc, int n, float invN) {
    int i = threadIdx.x;
    if (i < n) {
        float mu = sum[i] * invN;
        float var = ssq[i] * invN - mu * mu;
        float rs = rsqrtf(var + BNE);
        float gg = g[i];
        float bb = b[i];
        a[i] = rs * gg;
        cc[i] = bb - mu * rs * gg;
    }
}

// ---------------- final: out = relu(x0 + (y*a2+c2)) + eps (float4) ----------------
__global__ void final_k(const float4* __restrict__ x0, const float4* __restrict__ y,
                        const float* __restrict__ a2, const float* __restrict__ c2,
                        float4* __restrict__ outp, int total4) {
    int i = blockIdx.x * 256 + threadIdx.x;
    if (i >= total4) return;
    int c0 = (i * 4) & 63;
    float4 yv = y[i], xv = x0[i];
    float4 o;
    o.x = fmaxf(xv.x + yv.x * a2[c0 + 0] + c2[c0 + 0], 0.f) + FEPS;
    o.y = fmaxf(xv.y + yv.y * a2[c0 + 1] + c2[c0 + 1], 0.f) + FEPS;
    o.z = fmaxf(xv.z + yv.z * a2[c0 + 2] + c2[c0 + 2], 0.f) + FEPS;
    o.w = fmaxf(xv.w + yv.w * a2[c0 + 3] + c2[c0 + 3], 0.f) + FEPS;
    outp[i] = o;
}

extern "C" void kernel_launch(void* const* d_in, const int* in_sizes, int n_in,
                              void* d_out, int out_size, void* d_ws, size_t ws_size,
                              hipStream_t stream) {
    const float* x0 = (const float*)d_in[0];
    const int* ei = (const int*)d_in[1];
    const float* t = (const float*)d_in[2];
    const float* scale = (const float*)d_in[3];
    const float* W1 = (const float*)d_in[4];
    const float* b1 = (const float*)d_in[5];
    const float* g1 = (const float*)d_in[6];
    const float* be1 = (const float*)d_in[7];
    const float* W2 = (const float*)d_in[8];
    const float* b2 = (const float*)d_in[9];
    const float* bn_g = (const float*)d_in[10];
    const float* bn_b = (const float*)d_in[11];

    const int N = in_sizes[0] / C;
    const int E = in_sizes[1] / 2;
    const int* src = ei;
    const int* dst = ei + E;
    const int NB = (N + BSZ - 1) >> BSH;   // 196 buckets (<=256)

    char* ws = (char*)d_ws;
    size_t cur = 0;
    auto alloc = [&](size_t bytes) -> char* {
        char* p = ws + cur;
        cur = (cur + bytes + 255) & ~(size_t)255;
        return p;
    };
    int* bucket_cnt = (int*)alloc(256 * 4);
    float* stats = (float*)alloc(768 * 4);          // [layer][sum1 128|ssq1 128|sum2 64|ssq2 64]
    int* dbin = (int*)alloc(64 * 4);
    size_t zbytes = cur;                            // zero only atomic targets
    float* params = (float*)alloc(768 * 4);         // [layer][a1 128|c1 128|a2 64|c2 64]
    int* bucket_off = (int*)alloc(257 * 4);
    int* bucket_fill = (int*)alloc(256 * 4);
    int* dbfill = (int*)alloc(64 * 4);
    int* perm = (int*)alloc((size_t)N * 4);
    int* row_start = (int*)alloc(((size_t)N + 1) * 4);
    int* col = (int*)alloc((size_t)E * 4);
    ushort* marr = (ushort*)alloc((size_t)N * C * 2);    // bf16 messages
    ushort* wt1 = (ushort*)alloc(2 * H * C * 2);         // Wt1[2][128cols][64k] bf16
    ushort* wt2 = (ushort*)alloc(2 * C * H * 2);         // Wt2[2][64cols][128k] bf16
    float* bout = (float*)alloc((size_t)N * C * 4);
    ushort* bh = (ushort*)alloc((size_t)N * H * 2);      // h as bf16
    float* by = (float*)alloc((size_t)N * C * 4);
    // bpak aliases bh: CSR build finishes before first mlpm writes bh (E*4 <= N*H*2)
    unsigned int* bpak = (unsigned int*)bh;

    hipMemsetAsync(d_ws, 0, zbytes, stream);

    // weight pre-transpose (once)
    wprep_k<<<128, 256, 0, stream>>>(W1, W2, wt1, wt2);

    // CSR build (bucketed, packed scatter)
    int nbE = (E + EPB - 1) / EPB;
    bhist_k<<<nbE, 256, 0, stream>>>(dst, bucket_cnt, E, NB);
    bscan_k<<<1, 256, 0, stream>>>(bucket_cnt, bucket_off, bucket_fill, row_start, NB, N, E);
    bscat_k<<<nbE, 256, 0, stream>>>(src, dst, bucket_fill, bpak, E);
    bfine_k<<<NB, 512, 0, stream>>>(bucket_off, bpak, row_start, col, N);

    // degree-sorted node permutation
    int nbD = (N + 1023) / 1024;
    dhist_k<<<nbD, 256, 0, stream>>>(row_start, dbin, N);
    dscan_k<<<1, 64, 0, stream>>>(dbin, dbfill);
    dscat_k<<<nbD, 256, 0, stream>>>(row_start, dbfill, perm, N);

    float* sum1_0 = stats + 0;   float* ssq1_0 = stats + 128;
    float* sum2_0 = stats + 256; float* ssq2_0 = stats + 320;
    float* sum1_1 = stats + 384; float* ssq1_1 = stats + 512;
    float* sum2_1 = stats + 640; float* ssq2_1 = stats + 704;
    float* a1_0 = params + 0;   float* c1_0 = params + 128;
    float* a2_0 = params + 256; float* c2_0 = params + 320;
    float* a1_1 = params + 384; float* c1_1 = params + 512;
    float* a2_1 = params + 640; float* c2_1 = params + 704;

    const float invN = 1.0f / (float)N;
    int nbN16 = (N + 15) / 16;            // agg: 16 nodes per block
    int nbT2 = (N + 127) / 128;           // GEMM row tiles (BM=128)
    int nbP = (N * C / 4 + 255) / 256;    // prep/final

    // ---- layer 0 ----
    prep_k<0><<<nbP, 256, 0, stream>>>(x0, nullptr, nullptr, marr, N * C / 4);
    agg_k<0><<<nbN16, 256, 0, stream>>>(x0, nullptr, nullptr,
                                        (const uint2*)marr, row_start, col, perm,
                                        t, scale, 0, bout, N);
    mlpm_k<C, H, 0><<<nbT2, 256, 0, stream>>>(bout, nullptr, nullptr, wt1, b1, bh,
                                              sum1_0, ssq1_0, N);
    bnfin_k<<<1, 128, 0, stream>>>(sum1_0, ssq1_0, g1, be1, a1_0, c1_0, H, invN);
    mlpm_k<H, C, 1><<<nbT2, 256, 0, stream>>>(bh, a1_0, c1_0, wt2, b2, by,
                                              sum2_0, ssq2_0, N);
    bnfin_k<<<1, 64, 0, stream>>>(sum2_0, ssq2_0, bn_g, bn_b, a2_0, c2_0, C, invN);

    // ---- layer 1 ----
    prep_k<1><<<nbP, 256, 0, stream>>>(by, a2_0, c2_0, marr, N * C / 4);
    agg_k<1><<<nbN16, 256, 0, stream>>>(by, a2_0, c2_0,
                                        (const uint2*)marr, row_start, col, perm,
                                        t, scale, 1, bout, N);
    mlpm_k<C, H, 0><<<nbT2, 256, 0, stream>>>(bout, nullptr, nullptr, wt1 + H * C, b1 + H, bh,
                                              sum1_1, ssq1_1, N);
    bnfin_k<<<1, 128, 0, stream>>>(sum1_1, ssq1_1, g1 + H, be1 + H, a1_1, c1_1, H, invN);
    mlpm_k<H, C, 1><<<nbT2, 256, 0, stream>>>(bh, a1_1, c1_1, wt2 + C * H, b2 + C, by,
                                              sum2_1, ssq2_1, N);
    bnfin_k<<<1, 64, 0, stream>>>(sum2_1, ssq2_1, bn_g + C, bn_b + C, a2_1, c2_1, C, invN);

    // ---- residual + relu + eps ----
    final_k<<<nbP, 256, 0, stream>>>((const float4*)x0, (const float4*)by, a2_1, c2_1,
                                     (float4*)d_out, N * C / 4);
}

// Round 16
// 330.967 us; speedup vs baseline: 1.0453x; 1.0453x over previous
//
#include <hip/hip_runtime.h>
#include <hip/hip_bf16.h>

#define C 64
#define H 128
#define FEPS 1e-7f
#define BNE 1e-5f
#define BSH 9
#define BSZ 512   // nodes per bucket
#define EPB 4096  // edges per block in bhist/bscat

typedef __attribute__((ext_vector_type(8))) short bf16x8;
typedef __attribute__((ext_vector_type(4))) float f32x4;

__device__ __forceinline__ float us2f(ushort u) {
    unsigned int x = ((unsigned int)u) << 16;
    return __uint_as_float(x);
}
__device__ __forceinline__ ushort f2us(float f) {
    __hip_bfloat16 h = __float2bfloat16(f);
    return *reinterpret_cast<ushort*>(&h);
}
// BN affine from raw sums: a = rsqrt(var+eps)*g ; c = b - mu*a
__device__ __forceinline__ void bnaff(const float* __restrict__ sum,
                                      const float* __restrict__ ssq,
                                      const float* __restrict__ g,
                                      const float* __restrict__ b,
                                      float invN, int ch, float& a, float& c) {
    float mu = sum[ch] * invN;
    float var = ssq[ch] * invN - mu * mu;
    float rs = rsqrtf(var + BNE);
    a = rs * g[ch];
    c = b[ch] - mu * a;
}

// ---------------- CSR build (bucketed; packed (loc,src) scatter word) ----------------
__global__ __launch_bounds__(256) void bhist_k(const int* __restrict__ dst,
                                               int* __restrict__ bucket_cnt, int E, int NB) {
    __shared__ int cnt[256];
    int tid = threadIdx.x;
    cnt[tid] = 0;
    __syncthreads();
    int base = blockIdx.x * EPB;
#pragma unroll
    for (int j = 0; j < 16; j++) {
        int e = base + tid + j * 256;
        if (e < E) atomicAdd(&cnt[dst[e] >> BSH], 1);
    }
    __syncthreads();
    if (tid < NB && cnt[tid]) atomicAdd(&bucket_cnt[tid], cnt[tid]);
}

__global__ void bscan_k(const int* __restrict__ bucket_cnt, int* __restrict__ bucket_off,
                        int* __restrict__ bucket_fill, int* __restrict__ row_start,
                        int NB, int N, int E) {
    __shared__ int s[256];
    int tid = threadIdx.x;
    int v = (tid < NB) ? bucket_cnt[tid] : 0;
    s[tid] = v;
    __syncthreads();
    for (int off = 1; off < 256; off <<= 1) {
        int t = 0;
        if (tid >= off) t = s[tid - off];
        __syncthreads();
        s[tid] += t;
        __syncthreads();
    }
    int excl = s[tid] - v;
    if (tid < NB) { bucket_off[tid] = excl; bucket_fill[tid] = excl; }
    if (tid == NB - 1) bucket_off[NB] = s[tid];
    if (tid == 0) row_start[N] = E;
}

// packed word: (dst & (BSZ-1)) << 17 | src   (requires N < 2^17 = 131072)
__global__ __launch_bounds__(256) void bscat_k(const int* __restrict__ src,
                                               const int* __restrict__ dst,
                                               int* __restrict__ bucket_fill,
                                               unsigned int* __restrict__ bpak, int E) {
    __shared__ int cnt[256];
    __shared__ int sbase[256];
    int tid = threadIdx.x;
    cnt[tid] = 0;
    __syncthreads();
    int base = blockIdx.x * EPB;
    int dd[16], rk[16];
#pragma unroll
    for (int j = 0; j < 16; j++) {
        int e = base + tid + j * 256;
        dd[j] = -1;
        if (e < E) {
            int d = dst[e];
            dd[j] = d;
            rk[j] = atomicAdd(&cnt[d >> BSH], 1);
        }
    }
    __syncthreads();
    if (cnt[tid]) sbase[tid] = atomicAdd(&bucket_fill[tid], cnt[tid]);
    __syncthreads();
#pragma unroll
    for (int j = 0; j < 16; j++) {
        if (dd[j] >= 0) {
            int e = base + tid + j * 256;
            int b = dd[j] >> BSH;
            int pos = sbase[b] + rk[j];
            bpak[pos] = ((unsigned int)(dd[j] & (BSZ - 1)) << 17) | (unsigned int)src[e];
        }
    }
}

__global__ __launch_bounds__(512) void bfine_k(const int* __restrict__ bucket_off,
                                               const unsigned int* __restrict__ bpak,
                                               int* __restrict__ row_start,
                                               int* __restrict__ col, int N) {
    __shared__ int cnt[BSZ];
    __shared__ int off[BSZ];
    __shared__ int fill[BSZ];
    int tid = threadIdx.x;
    int b = blockIdx.x;
    int e0 = bucket_off[b], e1 = bucket_off[b + 1];
    int nbase = b << BSH;
    cnt[tid] = 0; fill[tid] = 0;
    __syncthreads();
    for (int e = e0 + tid; e < e1; e += 512) atomicAdd(&cnt[bpak[e] >> 17], 1);
    __syncthreads();
    int v = cnt[tid];
    off[tid] = v;
    __syncthreads();
    for (int o = 1; o < 512; o <<= 1) {
        int t = 0;
        if (tid >= o) t = off[tid - o];
        __syncthreads();
        off[tid] += t;
        __syncthreads();
    }
    int excl = off[tid] - v;
    off[tid] = excl;
    __syncthreads();
    int n = nbase + tid;
    if (n < N) row_start[n] = e0 + excl;
    for (int e = e0 + tid; e < e1; e += 512) {
        unsigned int w = bpak[e];
        int loc = w >> 17;
        int r = atomicAdd(&fill[loc], 1);
        col[e0 + off[loc] + r] = (int)(w & 0x1FFFFu);
    }
}

// ---------------- message prep: marr = bf16(relu(x)+eps); AFF folds BN from stats ----------------
template <int AFF>
__global__ __launch_bounds__(256) void prep_k(const float* __restrict__ in,
                                              const float* __restrict__ sum,
                                              const float* __restrict__ ssq,
                                              const float* __restrict__ g,
                                              const float* __restrict__ b,
                                              float invN,
                                              ushort* __restrict__ marr, int total4) {
    int i = blockIdx.x * 256 + threadIdx.x;
    if (i >= total4) return;
    float4 v = ((const float4*)in)[i];
    int c0 = (i * 4) & 63;
    float vv[4] = {v.x, v.y, v.z, v.w};
    ushort u[4];
#pragma unroll
    for (int j = 0; j < 4; j++) {
        float x = vv[j];
        if (AFF) {
            float a, cc;
            bnaff(sum, ssq, g, b, invN, c0 + j, a, cc);
            float xv = fmaxf(x * a + cc, 0.f) + FEPS;
            x = xv + FEPS;
        } else {
            x = fmaxf(x, 0.f) + FEPS;
        }
        u[j] = f2us(x);
    }
    ushort4 uv = make_ushort4(u[0], u[1], u[2], u[3]);
    ((ushort4*)marr)[i] = uv;
}

// ---------------- fused softmax-aggregation + MessageNorm ----------------
// Quarter-per-node (sequential order); col int4-prefetched one iter ahead; 8 gathers in flight.
// MODE 1 folds BN affine (from stats) + relu + eps into the self term.
template <int MODE>
__global__ __launch_bounds__(256) void agg_k(const float* __restrict__ xin,
                                             const float* __restrict__ sum,
                                             const float* __restrict__ ssq,
                                             const float* __restrict__ g,
                                             const float* __restrict__ b,
                                             float invN,
                                             const uint2* __restrict__ marr64,
                                             const int* __restrict__ rs,
                                             const int* __restrict__ col,
                                             const float* __restrict__ t,
                                             const float* __restrict__ sc,
                                             int layer, float* __restrict__ outb, int N) {
    int lane = threadIdx.x & 63;
    int wid = threadIdx.x >> 6;
    int q = lane >> 4;      // quarter 0..3 -> node
    int ql = lane & 15;     // owns channels 4ql..4ql+3
    int n = blockIdx.x * 16 + wid * 4 + q;
    if (n >= N) return;
    float tv = t[layer];
    float sv = sc[layer];

    int beg = rs[n], end = rs[n + 1];
    float den[4] = {0.f, 0.f, 0.f, 0.f}, num[4] = {0.f, 0.f, 0.f, 0.f};

    auto acc4 = [&](uint2 d) {
        float m0 = __uint_as_float(d.x << 16);
        float m1 = __uint_as_float(d.x & 0xffff0000u);
        float m2 = __uint_as_float(d.y << 16);
        float m3 = __uint_as_float(d.y & 0xffff0000u);
        float e0 = __expf(m0 * tv);
        float e1 = __expf(m1 * tv);
        float e2 = __expf(m2 * tv);
        float e3 = __expf(m3 * tv);
        den[0] += e0; num[0] += m0 * e0;
        den[1] += e1; num[1] += m1 * e1;
        den[2] += e2; num[2] += m2 * e2;
        den[3] += e3; num[3] += m3 * e3;
    };

    int e = beg;
    // scalar head to 16B-align col pointer
    int head = (4 - (e & 3)) & 3;
    if (head > end - e) head = end - e;
    for (int i = 0; i < head; i++, e++) {
        uint2 d0 = marr64[(size_t)col[e] * 16 + ql];
        acc4(d0);
    }
    if (e + 8 <= end) {
        int4 ca = *(const int4*)(col + e);
        int4 cb = *(const int4*)(col + e + 4);
        while (true) {
            uint2 d0 = marr64[(size_t)ca.x * 16 + ql];
            uint2 d1 = marr64[(size_t)ca.y * 16 + ql];
            uint2 d2 = marr64[(size_t)ca.z * 16 + ql];
            uint2 d3 = marr64[(size_t)ca.w * 16 + ql];
            uint2 d4 = marr64[(size_t)cb.x * 16 + ql];
            uint2 d5 = marr64[(size_t)cb.y * 16 + ql];
            uint2 d6 = marr64[(size_t)cb.z * 16 + ql];
            uint2 d7 = marr64[(size_t)cb.w * 16 + ql];
            e += 8;
            bool more = (e + 8 <= end);
            if (more) {
                ca = *(const int4*)(col + e);
                cb = *(const int4*)(col + e + 4);
            }
            acc4(d0); acc4(d1); acc4(d2); acc4(d3);
            acc4(d4); acc4(d5); acc4(d6); acc4(d7);
            if (!more) break;
        }
    }
    for (; e < end; e++) {
        uint2 d0 = marr64[(size_t)col[e] * 16 + ql];
        acc4(d0);
    }

    float agg[4], aq = 0.f;
#pragma unroll
    for (int c = 0; c < 4; c++) {
        agg[c] = (den[c] > 0.f) ? (num[c] / den[c]) : 0.f;
        aq += agg[c] * agg[c];
    }

    float4 xv = ((const float4*)xin)[(size_t)n * 16 + ql];
    float xn[4];
    if (MODE == 0) {
        xn[0] = xv.x; xn[1] = xv.y; xn[2] = xv.z; xn[3] = xv.w;
    } else {
        float vv[4] = {xv.x, xv.y, xv.z, xv.w};
#pragma unroll
        for (int j = 0; j < 4; j++) {
            float a, cc;
            bnaff(sum, ssq, g, b, invN, 4 * ql + j, a, cc);
            xn[j] = fmaxf(vv[j] * a + cc, 0.f) + FEPS;
        }
    }
    float xq = xn[0] * xn[0] + xn[1] * xn[1] + xn[2] * xn[2] + xn[3] * xn[3];
    float na = aq, nx = xq;
#pragma unroll
    for (int m = 1; m <= 8; m <<= 1) {
        na += __shfl_xor(na, m, 64);
        nx += __shfl_xor(nx, m, 64);
    }
    float s = (1.0f / fmaxf(sqrtf(na), 1e-12f)) * sqrtf(nx) * sv;
    float4 o;
    o.x = xn[0] + agg[0] * s;
    o.y = xn[1] + agg[1] * s;
    o.z = xn[2] + agg[2] * s;
    o.w = xn[3] + agg[3] * s;
    ((float4*)outb)[(size_t)n * 16 + ql] = o;
}

// ---------------- weight pre-transpose: Wt[col][k] bf16 (once per call) ----------------
__global__ void wprep_k(const float* __restrict__ W1, const float* __restrict__ W2,
                        ushort* __restrict__ wt1, ushort* __restrict__ wt2) {
    int idx = blockIdx.x * 256 + threadIdx.x;   // 0..32767
    int m = idx >> 13, w = idx & 8191;
    if (m < 2) {
        int colw = w >> 6, k = w & 63;
        wt1[idx] = f2us(W1[m * 8192 + k * 128 + colw]);
    } else {
        int l = m - 2;
        int colw = w >> 7, k = w & 127;
        wt2[l * 8192 + w] = f2us(W2[l * 8192 + k * 64 + colw]);
    }
}

// ---------------- MFMA MLP GEMM: barrier-free streaming, both row-tiles prefetched ----------------
// MODE 1: BN affine computed from stats into LDS faf at block start.
template <int KD, int ND, int MODE>
__global__ __launch_bounds__(256) void mlpm_k(const void* __restrict__ Ain,
                                              const float* __restrict__ sum,
                                              const float* __restrict__ ssq,
                                              const float* __restrict__ g,
                                              const float* __restrict__ b,
                                              float invN,
                                              const ushort* __restrict__ WtT,
                                              const float* __restrict__ bias,
                                              void* __restrict__ outp,
                                              float* __restrict__ s_sum,
                                              float* __restrict__ s_ssq, int N) {
    constexpr int NT = ND / 16;   // col tiles
    constexpr int KS = KD / 32;   // k slices
    __shared__ float ssum[ND], sssq[ND];
    __shared__ float faf[MODE ? KD : 1][2];
    int tid = threadIdx.x;
    int wave = tid >> 6, lane = tid & 63, lrow = lane & 15, kg = lane >> 4;
    if (tid < ND) { ssum[tid] = 0.f; sssq[tid] = 0.f; }
    if (MODE) {
        for (int i = tid; i < KD; i += 256) {
            float a, cc;
            bnaff(sum, ssq, g, b, invN, i, a, cc);
            faf[i][0] = a; faf[i][1] = cc;
        }
    }
    __syncthreads();

    int base = blockIdx.x * 128;

    bf16x8 wfr[NT][KS];
#pragma unroll
    for (int t = 0; t < NT; t++)
#pragma unroll
        for (int ks = 0; ks < KS; ks++)
            wfr[t][ks] = *(const bf16x8*)(WtT + (t * 16 + lrow) * KD + ks * 32 + kg * 8);
    float bv[NT];
#pragma unroll
    for (int t = 0; t < NT; t++) bv[t] = bias[t * 16 + lrow];

    float ls[NT], lq[NT];
#pragma unroll
    for (int t = 0; t < NT; t++) { ls[t] = 0.f; lq[t] = 0.f; }

    // ---- load BOTH row-tiles' A data before converting/computing ----
    bf16x8 afr[2][KS];
    if (MODE == 0) {
        float4 raw[2][KS][2];
#pragma unroll
        for (int rt = 0; rt < 2; rt++) {
            int arow = base + (wave * 2 + rt) * 16 + lrow;
            bool rok = arow < N;
#pragma unroll
            for (int ks = 0; ks < KS; ks++) {
                float4 z = make_float4(0.f, 0.f, 0.f, 0.f);
                raw[rt][ks][0] = z; raw[rt][ks][1] = z;
                if (rok) {
                    const float4* p = (const float4*)((const float*)Ain +
                                                      (size_t)arow * KD + ks * 32 + kg * 8);
                    raw[rt][ks][0] = p[0];
                    raw[rt][ks][1] = p[1];
                }
            }
        }
#pragma unroll
        for (int rt = 0; rt < 2; rt++)
#pragma unroll
            for (int ks = 0; ks < KS; ks++) {
                float4 v0 = raw[rt][ks][0], v1 = raw[rt][ks][1];
                bf16x8 a;
                a[0] = (short)f2us(v0.x); a[1] = (short)f2us(v0.y);
                a[2] = (short)f2us(v0.z); a[3] = (short)f2us(v0.w);
                a[4] = (short)f2us(v1.x); a[5] = (short)f2us(v1.y);
                a[6] = (short)f2us(v1.z); a[7] = (short)f2us(v1.w);
                afr[rt][ks] = a;
            }
    } else {
        uint4 raw[2][KS];
#pragma unroll
        for (int rt = 0; rt < 2; rt++) {
            int arow = base + (wave * 2 + rt) * 16 + lrow;
            bool rok = arow < N;
#pragma unroll
            for (int ks = 0; ks < KS; ks++) {
                raw[rt][ks] = make_uint4(0u, 0u, 0u, 0u);
                if (rok) raw[rt][ks] = *(const uint4*)((const ushort*)Ain +
                                                       (size_t)arow * KD + ks * 32 + kg * 8);
            }
        }
#pragma unroll
        for (int rt = 0; rt < 2; rt++)
#pragma unroll
            for (int ks = 0; ks < KS; ks++) {
                int k0 = ks * 32 + kg * 8;
                unsigned int w[4] = {raw[rt][ks].x, raw[rt][ks].y, raw[rt][ks].z, raw[rt][ks].w};
                bf16x8 a;
#pragma unroll
                for (int p = 0; p < 4; p++) {
                    float f0 = us2f((ushort)(w[p] & 0xffffu));
                    float f1 = us2f((ushort)(w[p] >> 16));
                    f0 = fmaxf(f0 * faf[k0 + 2 * p][0] + faf[k0 + 2 * p][1], 0.f);
                    f1 = fmaxf(f1 * faf[k0 + 2 * p + 1][0] + faf[k0 + 2 * p + 1][1], 0.f);
                    a[2 * p] = (short)f2us(f0);
                    a[2 * p + 1] = (short)f2us(f1);
                }
                afr[rt][ks] = a;
            }
    }

#pragma unroll
    for (int rt = 0; rt < 2; rt++) {
        int tidx = wave * 2 + rt;
#pragma unroll
        for (int t = 0; t < NT; t++) {
            f32x4 acc = {0.f, 0.f, 0.f, 0.f};
#pragma unroll
            for (int ks = 0; ks < KS; ks++)
                acc = __builtin_amdgcn_mfma_f32_16x16x32_bf16(afr[rt][ks], wfr[t][ks], acc, 0, 0, 0);
            int colw = t * 16 + lrow;
#pragma unroll
            for (int r = 0; r < 4; r++) {
                int orow = base + tidx * 16 + kg * 4 + r;
                float v = acc[r] + bv[t];
                if (orow < N) {
                    if (MODE == 0) ((ushort*)outp)[(size_t)orow * ND + colw] = f2us(v);
                    else ((float*)outp)[(size_t)orow * ND + colw] = v;
                    ls[t] += v; lq[t] += v * v;
                }
            }
        }
    }

#pragma unroll
    for (int t = 0; t < NT; t++) {
        float a = ls[t], bq = lq[t];
        a += __shfl_xor(a, 16, 64); a += __shfl_xor(a, 32, 64);
        bq += __shfl_xor(bq, 16, 64); bq += __shfl_xor(bq, 32, 64);
        if (kg == 0) {
            atomicAdd(&ssum[t * 16 + lrow], a);
            atomicAdd(&sssq[t * 16 + lrow], bq);
        }
    }
    __syncthreads();
    if (tid < ND) {
        atomicAdd(&s_sum[tid], ssum[tid]);
        atomicAdd(&s_ssq[tid], sssq[tid]);
    }
}

// ---------------- final: out = relu(x0 + BN(y)) + eps (BN affine from stats) ----------------
__global__ void final_k(const float4* __restrict__ x0, const float4* __restrict__ y,
                        const float* __restrict__ sum, const float* __restrict__ ssq,
                        const float* __restrict__ g, const float* __restrict__ b,
                        float invN, float4* __restrict__ outp, int total4) {
    int i = blockIdx.x * 256 + threadIdx.x;
    if (i >= total4) return;
    int c0 = (i * 4) & 63;
    float4 yv = y[i], xv = x0[i];
    float yy[4] = {yv.x, yv.y, yv.z, yv.w};
    float xx[4] = {xv.x, xv.y, xv.z, xv.w};
    float oo[4];
#pragma unroll
    for (int j = 0; j < 4; j++) {
        float a, cc;
        bnaff(sum, ssq, g, b, invN, c0 + j, a, cc);
        oo[j] = fmaxf(xx[j] + yy[j] * a + cc, 0.f) + FEPS;
    }
    float4 o = make_float4(oo[0], oo[1], oo[2], oo[3]);
    outp[i] = o;
}

extern "C" void kernel_launch(void* const* d_in, const int* in_sizes, int n_in,
                              void* d_out, int out_size, void* d_ws, size_t ws_size,
                              hipStream_t stream) {
    const float* x0 = (const float*)d_in[0];
    const int* ei = (const int*)d_in[1];
    const float* t = (const float*)d_in[2];
    const float* scale = (const float*)d_in[3];
    const float* W1 = (const float*)d_in[4];
    const float* b1 = (const float*)d_in[5];
    const float* g1 = (const float*)d_in[6];
    const float* be1 = (const float*)d_in[7];
    const float* W2 = (const float*)d_in[8];
    const float* b2 = (const float*)d_in[9];
    const float* bn_g = (const float*)d_in[10];
    const float* bn_b = (const float*)d_in[11];

    const int N = in_sizes[0] / C;
    const int E = in_sizes[1] / 2;
    const int* src = ei;
    const int* dst = ei + E;
    const int NB = (N + BSZ - 1) >> BSH;   // 196 buckets (<=256)

    char* ws = (char*)d_ws;
    size_t cur = 0;
    auto alloc = [&](size_t bytes) -> char* {
        char* p = ws + cur;
        cur = (cur + bytes + 255) & ~(size_t)255;
        return p;
    };
    int* bucket_cnt = (int*)alloc(256 * 4);
    float* stats = (float*)alloc(768 * 4);          // [layer][sum1 128|ssq1 128|sum2 64|ssq2 64]
    size_t zbytes = cur;                            // zero only atomic targets
    int* bucket_off = (int*)alloc(257 * 4);
    int* bucket_fill = (int*)alloc(256 * 4);
    int* row_start = (int*)alloc(((size_t)N + 1) * 4);
    int* col = (int*)alloc((size_t)E * 4);
    ushort* marr = (ushort*)alloc((size_t)N * C * 2);    // bf16 messages
    ushort* wt1 = (ushort*)alloc(2 * H * C * 2);         // Wt1[2][128cols][64k] bf16
    ushort* wt2 = (ushort*)alloc(2 * C * H * 2);         // Wt2[2][64cols][128k] bf16
    float* bout = (float*)alloc((size_t)N * C * 4);
    ushort* bh = (ushort*)alloc((size_t)N * H * 2);      // h as bf16
    float* by = (float*)alloc((size_t)N * C * 4);
    // bpak aliases bh: CSR build finishes before first mlpm writes bh (E*4 <= N*H*2)
    unsigned int* bpak = (unsigned int*)bh;

    hipMemsetAsync(d_ws, 0, zbytes, stream);

    // weight pre-transpose (once)
    wprep_k<<<128, 256, 0, stream>>>(W1, W2, wt1, wt2);

    // CSR build (bucketed, packed scatter)
    int nbE = (E + EPB - 1) / EPB;
    bhist_k<<<nbE, 256, 0, stream>>>(dst, bucket_cnt, E, NB);
    bscan_k<<<1, 256, 0, stream>>>(bucket_cnt, bucket_off, bucket_fill, row_start, NB, N, E);
    bscat_k<<<nbE, 256, 0, stream>>>(src, dst, bucket_fill, bpak, E);
    bfine_k<<<NB, 512, 0, stream>>>(bucket_off, bpak, row_start, col, N);

    float* sum1_0 = stats + 0;   float* ssq1_0 = stats + 128;
    float* sum2_0 = stats + 256; float* ssq2_0 = stats + 320;
    float* sum1_1 = stats + 384; float* ssq1_1 = stats + 512;
    float* sum2_1 = stats + 640; float* ssq2_1 = stats + 704;

    const float invN = 1.0f / (float)N;
    int nbN16 = (N + 15) / 16;            // agg: 16 nodes per block
    int nbT2 = (N + 127) / 128;           // GEMM row tiles (BM=128)
    int nbP = (N * C / 4 + 255) / 256;    // prep/final

    // ---- layer 0 ----
    prep_k<0><<<nbP, 256, 0, stream>>>(x0, nullptr, nullptr, nullptr, nullptr, 0.f,
                                       marr, N * C / 4);
    agg_k<0><<<nbN16, 256, 0, stream>>>(x0, nullptr, nullptr, nullptr, nullptr, 0.f,
                                        (const uint2*)marr, row_start, col,
                                        t, scale, 0, bout, N);
    mlpm_k<C, H, 0><<<nbT2, 256, 0, stream>>>(bout, nullptr, nullptr, nullptr, nullptr, 0.f,
                                              wt1, b1, bh, sum1_0, ssq1_0, N);
    mlpm_k<H, C, 1><<<nbT2, 256, 0, stream>>>(bh, sum1_0, ssq1_0, g1, be1, invN,
                                              wt2, b2, by, sum2_0, ssq2_0, N);

    // ---- layer 1 ----
    prep_k<1><<<nbP, 256, 0, stream>>>(by, sum2_0, ssq2_0, bn_g, bn_b, invN,
                                       marr, N * C / 4);
    agg_k<1><<<nbN16, 256, 0, stream>>>(by, sum2_0, ssq2_0, bn_g, bn_b, invN,
                                        (const uint2*)marr, row_start, col,
                                        t, scale, 1, bout, N);
    mlpm_k<C, H, 0><<<nbT2, 256, 0, stream>>>(bout, nullptr, nullptr, nullptr, nullptr, 0.f,
                                              wt1 + H * C, b1 + H, bh, sum1_1, ssq1_1, N);
    mlpm_k<H, C, 1><<<nbT2, 256, 0, stream>>>(bh, sum1_1, ssq1_1, g1 + H, be1 + H, invN,
                                              wt2 + C * H, b2 + C, by, sum2_1, ssq2_1, N);

    // ---- residual + relu + eps (BN folded) ----
    final_k<<<nbP, 256, 0, stream>>>((const float4*)x0, (const float4*)by,
                                     sum2_1, ssq2_1, bn_g + C, bn_b + C, invN,
                                     (float4*)d_out, N * C / 4);
}

// Round 17
// 314.193 us; speedup vs baseline: 1.1011x; 1.0534x over previous
//
#include <hip/hip_runtime.h>
#include <hip/hip_bf16.h>

#define C 64
#define H 128
#define FEPS 1e-7f
#define BNE 1e-5f
#define BSH 9
#define BSZ 512   // nodes per bucket
#define EPB 4096  // edges per block in bhist/bscat

typedef __attribute__((ext_vector_type(8))) short bf16x8;
typedef __attribute__((ext_vector_type(4))) float f32x4;

__device__ __forceinline__ float us2f(ushort u) {
    unsigned int x = ((unsigned int)u) << 16;
    return __uint_as_float(x);
}
__device__ __forceinline__ ushort f2us(float f) {
    __hip_bfloat16 h = __float2bfloat16(f);
    return *reinterpret_cast<ushort*>(&h);
}
// BN affine from raw sums: a = rsqrt(var+eps)*g ; c = b - mu*a
__device__ __forceinline__ void bnaff(const float* __restrict__ sum,
                                      const float* __restrict__ ssq,
                                      const float* __restrict__ g,
                                      const float* __restrict__ b,
                                      float invN, int ch, float& a, float& c) {
    float mu = sum[ch] * invN;
    float var = ssq[ch] * invN - mu * mu;
    float rs = rsqrtf(var + BNE);
    a = rs * g[ch];
    c = b[ch] - mu * a;
}

// ---------------- CSR build (bucketed; packed (loc,src) scatter word) ----------------
__global__ __launch_bounds__(256) void bhist_k(const int* __restrict__ dst,
                                               int* __restrict__ bucket_cnt, int E, int NB) {
    __shared__ int cnt[256];
    int tid = threadIdx.x;
    cnt[tid] = 0;
    __syncthreads();
    int base = blockIdx.x * EPB;
#pragma unroll
    for (int j = 0; j < 16; j++) {
        int e = base + tid + j * 256;
        if (e < E) atomicAdd(&cnt[dst[e] >> BSH], 1);
    }
    __syncthreads();
    if (tid < NB && cnt[tid]) atomicAdd(&bucket_cnt[tid], cnt[tid]);
}

__global__ void bscan_k(const int* __restrict__ bucket_cnt, int* __restrict__ bucket_off,
                        int* __restrict__ bucket_fill, int* __restrict__ row_start,
                        int NB, int N, int E) {
    __shared__ int s[256];
    int tid = threadIdx.x;
    int v = (tid < NB) ? bucket_cnt[tid] : 0;
    s[tid] = v;
    __syncthreads();
    for (int off = 1; off < 256; off <<= 1) {
        int t = 0;
        if (tid >= off) t = s[tid - off];
        __syncthreads();
        s[tid] += t;
        __syncthreads();
    }
    int excl = s[tid] - v;
    if (tid < NB) { bucket_off[tid] = excl; bucket_fill[tid] = excl; }
    if (tid == NB - 1) bucket_off[NB] = s[tid];
    if (tid == 0) row_start[N] = E;
}

// packed word: (dst & (BSZ-1)) << 17 | src   (requires N < 2^17 = 131072)
__global__ __launch_bounds__(256) void bscat_k(const int* __restrict__ src,
                                               const int* __restrict__ dst,
                                               int* __restrict__ bucket_fill,
                                               unsigned int* __restrict__ bpak, int E) {
    __shared__ int cnt[256];
    __shared__ int sbase[256];
    int tid = threadIdx.x;
    cnt[tid] = 0;
    __syncthreads();
    int base = blockIdx.x * EPB;
    int dd[16], rk[16];
#pragma unroll
    for (int j = 0; j < 16; j++) {
        int e = base + tid + j * 256;
        dd[j] = -1;
        if (e < E) {
            int d = dst[e];
            dd[j] = d;
            rk[j] = atomicAdd(&cnt[d >> BSH], 1);
        }
    }
    __syncthreads();
    if (cnt[tid]) sbase[tid] = atomicAdd(&bucket_fill[tid], cnt[tid]);
    __syncthreads();
#pragma unroll
    for (int j = 0; j < 16; j++) {
        if (dd[j] >= 0) {
            int e = base + tid + j * 256;
            int b = dd[j] >> BSH;
            int pos = sbase[b] + rk[j];
            bpak[pos] = ((unsigned int)(dd[j] & (BSZ - 1)) << 17) | (unsigned int)src[e];
        }
    }
}

__global__ __launch_bounds__(512) void bfine_k(const int* __restrict__ bucket_off,
                                               const unsigned int* __restrict__ bpak,
                                               int* __restrict__ row_start,
                                               int* __restrict__ col, int N) {
    __shared__ int cnt[BSZ];
    __shared__ int off[BSZ];
    __shared__ int fill[BSZ];
    int tid = threadIdx.x;
    int b = blockIdx.x;
    int e0 = bucket_off[b], e1 = bucket_off[b + 1];
    int nbase = b << BSH;
    cnt[tid] = 0; fill[tid] = 0;
    __syncthreads();
    for (int e = e0 + tid; e < e1; e += 512) atomicAdd(&cnt[bpak[e] >> 17], 1);
    __syncthreads();
    int v = cnt[tid];
    off[tid] = v;
    __syncthreads();
    for (int o = 1; o < 512; o <<= 1) {
        int t = 0;
        if (tid >= o) t = off[tid - o];
        __syncthreads();
        off[tid] += t;
        __syncthreads();
    }
    int excl = off[tid] - v;
    off[tid] = excl;
    __syncthreads();
    int n = nbase + tid;
    if (n < N) row_start[n] = e0 + excl;
    for (int e = e0 + tid; e < e1; e += 512) {
        unsigned int w = bpak[e];
        int loc = w >> 17;
        int r = atomicAdd(&fill[loc], 1);
        col[e0 + off[loc] + r] = (int)(w & 0x1FFFFu);
    }
}

// ---------------- message prep: marr = bf16(relu(x)+eps); AFF folds BN from stats ----------------
template <int AFF>
__global__ __launch_bounds__(256) void prep_k(const float* __restrict__ in,
                                              const float* __restrict__ sum,
                                              const float* __restrict__ ssq,
                                              const float* __restrict__ g,
                                              const float* __restrict__ b,
                                              float invN,
                                              ushort* __restrict__ marr, int total4) {
    int i = blockIdx.x * 256 + threadIdx.x;
    if (i >= total4) return;
    float4 v = ((const float4*)in)[i];
    int c0 = (i * 4) & 63;
    float vv[4] = {v.x, v.y, v.z, v.w};
    ushort u[4];
#pragma unroll
    for (int j = 0; j < 4; j++) {
        float x = vv[j];
        if (AFF) {
            float a, cc;
            bnaff(sum, ssq, g, b, invN, c0 + j, a, cc);
            float xv = fmaxf(x * a + cc, 0.f) + FEPS;
            x = xv + FEPS;
        } else {
            x = fmaxf(x, 0.f) + FEPS;
        }
        u[j] = f2us(x);
    }
    ushort4 uv = make_ushort4(u[0], u[1], u[2], u[3]);
    ((ushort4*)marr)[i] = uv;
}

// ---------------- fused softmax-aggregation + MessageNorm ----------------
// Quarter-per-node (sequential, R14 loop form); 8 gathers in flight.
// MODE 1 folds BN affine (from stats) + relu + eps into the self term.
template <int MODE>
__global__ __launch_bounds__(256) void agg_k(const float* __restrict__ xin,
                                             const float* __restrict__ sum,
                                             const float* __restrict__ ssq,
                                             const float* __restrict__ g,
                                             const float* __restrict__ b,
                                             float invN,
                                             const uint2* __restrict__ marr64,
                                             const int* __restrict__ rs,
                                             const int* __restrict__ col,
                                             const float* __restrict__ t,
                                             const float* __restrict__ sc,
                                             int layer, float* __restrict__ outb, int N) {
    int lane = threadIdx.x & 63;
    int wid = threadIdx.x >> 6;
    int q = lane >> 4;      // quarter 0..3 -> node
    int ql = lane & 15;     // owns channels 4ql..4ql+3
    int n = blockIdx.x * 16 + wid * 4 + q;
    if (n >= N) return;
    float tv = t[layer];
    float sv = sc[layer];

    int beg = rs[n], end = rs[n + 1];
    float den[4] = {0.f, 0.f, 0.f, 0.f}, num[4] = {0.f, 0.f, 0.f, 0.f};

    auto acc4 = [&](uint2 d) {
        float m0 = __uint_as_float(d.x << 16);
        float m1 = __uint_as_float(d.x & 0xffff0000u);
        float m2 = __uint_as_float(d.y << 16);
        float m3 = __uint_as_float(d.y & 0xffff0000u);
        float e0 = __expf(m0 * tv);
        float e1 = __expf(m1 * tv);
        float e2 = __expf(m2 * tv);
        float e3 = __expf(m3 * tv);
        den[0] += e0; num[0] += m0 * e0;
        den[1] += e1; num[1] += m1 * e1;
        den[2] += e2; num[2] += m2 * e2;
        den[3] += e3; num[3] += m3 * e3;
    };

    int e = beg;
    for (; e + 8 <= end; e += 8) {
        uint2 d0 = marr64[(size_t)col[e + 0] * 16 + ql];
        uint2 d1 = marr64[(size_t)col[e + 1] * 16 + ql];
        uint2 d2 = marr64[(size_t)col[e + 2] * 16 + ql];
        uint2 d3 = marr64[(size_t)col[e + 3] * 16 + ql];
        uint2 d4 = marr64[(size_t)col[e + 4] * 16 + ql];
        uint2 d5 = marr64[(size_t)col[e + 5] * 16 + ql];
        uint2 d6 = marr64[(size_t)col[e + 6] * 16 + ql];
        uint2 d7 = marr64[(size_t)col[e + 7] * 16 + ql];
        acc4(d0); acc4(d1); acc4(d2); acc4(d3);
        acc4(d4); acc4(d5); acc4(d6); acc4(d7);
    }
    for (; e + 4 <= end; e += 4) {
        uint2 d0 = marr64[(size_t)col[e + 0] * 16 + ql];
        uint2 d1 = marr64[(size_t)col[e + 1] * 16 + ql];
        uint2 d2 = marr64[(size_t)col[e + 2] * 16 + ql];
        uint2 d3 = marr64[(size_t)col[e + 3] * 16 + ql];
        acc4(d0); acc4(d1); acc4(d2); acc4(d3);
    }
    for (; e < end; e++) {
        uint2 d0 = marr64[(size_t)col[e] * 16 + ql];
        acc4(d0);
    }

    float agg[4], aq = 0.f;
#pragma unroll
    for (int c = 0; c < 4; c++) {
        agg[c] = (den[c] > 0.f) ? (num[c] / den[c]) : 0.f;
        aq += agg[c] * agg[c];
    }

    float4 xv = ((const float4*)xin)[(size_t)n * 16 + ql];
    float xn[4];
    if (MODE == 0) {
        xn[0] = xv.x; xn[1] = xv.y; xn[2] = xv.z; xn[3] = xv.w;
    } else {
        float vv[4] = {xv.x, xv.y, xv.z, xv.w};
#pragma unroll
        for (int j = 0; j < 4; j++) {
            float a, cc;
            bnaff(sum, ssq, g, b, invN, 4 * ql + j, a, cc);
            xn[j] = fmaxf(vv[j] * a + cc, 0.f) + FEPS;
        }
    }
    float xq = xn[0] * xn[0] + xn[1] * xn[1] + xn[2] * xn[2] + xn[3] * xn[3];
    float na = aq, nx = xq;
#pragma unroll
    for (int m = 1; m <= 8; m <<= 1) {
        na += __shfl_xor(na, m, 64);
        nx += __shfl_xor(nx, m, 64);
    }
    float s = (1.0f / fmaxf(sqrtf(na), 1e-12f)) * sqrtf(nx) * sv;
    float4 o;
    o.x = xn[0] + agg[0] * s;
    o.y = xn[1] + agg[1] * s;
    o.z = xn[2] + agg[2] * s;
    o.w = xn[3] + agg[3] * s;
    ((float4*)outb)[(size_t)n * 16 + ql] = o;
}

// ---------------- weight pre-transpose: Wt[col][k] bf16 (once per call) ----------------
__global__ void wprep_k(const float* __restrict__ W1, const float* __restrict__ W2,
                        ushort* __restrict__ wt1, ushort* __restrict__ wt2) {
    int idx = blockIdx.x * 256 + threadIdx.x;   // 0..32767
    int m = idx >> 13, w = idx & 8191;
    if (m < 2) {
        int colw = w >> 6, k = w & 63;
        wt1[idx] = f2us(W1[m * 8192 + k * 128 + colw]);
    } else {
        int l = m - 2;
        int colw = w >> 7, k = w & 127;
        wt2[l * 8192 + w] = f2us(W2[l * 8192 + k * 64 + colw]);
    }
}

// ---------------- MFMA MLP GEMM: barrier-free streaming, both row-tiles prefetched ----------------
// MODE 1: BN affine computed from stats into LDS faf at block start.
template <int KD, int ND, int MODE>
__global__ __launch_bounds__(256) void mlpm_k(const void* __restrict__ Ain,
                                              const float* __restrict__ sum,
                                              const float* __restrict__ ssq,
                                              const float* __restrict__ g,
                                              const float* __restrict__ b,
                                              float invN,
                                              const ushort* __restrict__ WtT,
                                              const float* __restrict__ bias,
                                              void* __restrict__ outp,
                                              float* __restrict__ s_sum,
                                              float* __restrict__ s_ssq, int N) {
    constexpr int NT = ND / 16;   // col tiles
    constexpr int KS = KD / 32;   // k slices
    __shared__ float ssum[ND], sssq[ND];
    __shared__ float faf[MODE ? KD : 1][2];
    int tid = threadIdx.x;
    int wave = tid >> 6, lane = tid & 63, lrow = lane & 15, kg = lane >> 4;
    if (tid < ND) { ssum[tid] = 0.f; sssq[tid] = 0.f; }
    if (MODE) {
        for (int i = tid; i < KD; i += 256) {
            float a, cc;
            bnaff(sum, ssq, g, b, invN, i, a, cc);
            faf[i][0] = a; faf[i][1] = cc;
        }
    }
    __syncthreads();

    int base = blockIdx.x * 128;

    bf16x8 wfr[NT][KS];
#pragma unroll
    for (int t = 0; t < NT; t++)
#pragma unroll
        for (int ks = 0; ks < KS; ks++)
            wfr[t][ks] = *(const bf16x8*)(WtT + (t * 16 + lrow) * KD + ks * 32 + kg * 8);
    float bv[NT];
#pragma unroll
    for (int t = 0; t < NT; t++) bv[t] = bias[t * 16 + lrow];

    float ls[NT], lq[NT];
#pragma unroll
    for (int t = 0; t < NT; t++) { ls[t] = 0.f; lq[t] = 0.f; }

    // ---- load BOTH row-tiles' A data before converting/computing ----
    bf16x8 afr[2][KS];
    if (MODE == 0) {
        float4 raw[2][KS][2];
#pragma unroll
        for (int rt = 0; rt < 2; rt++) {
            int arow = base + (wave * 2 + rt) * 16 + lrow;
            bool rok = arow < N;
#pragma unroll
            for (int ks = 0; ks < KS; ks++) {
                float4 z = make_float4(0.f, 0.f, 0.f, 0.f);
                raw[rt][ks][0] = z; raw[rt][ks][1] = z;
                if (rok) {
                    const float4* p = (const float4*)((const float*)Ain +
                                                      (size_t)arow * KD + ks * 32 + kg * 8);
                    raw[rt][ks][0] = p[0];
                    raw[rt][ks][1] = p[1];
                }
            }
        }
#pragma unroll
        for (int rt = 0; rt < 2; rt++)
#pragma unroll
            for (int ks = 0; ks < KS; ks++) {
                float4 v0 = raw[rt][ks][0], v1 = raw[rt][ks][1];
                bf16x8 a;
                a[0] = (short)f2us(v0.x); a[1] = (short)f2us(v0.y);
                a[2] = (short)f2us(v0.z); a[3] = (short)f2us(v0.w);
                a[4] = (short)f2us(v1.x); a[5] = (short)f2us(v1.y);
                a[6] = (short)f2us(v1.z); a[7] = (short)f2us(v1.w);
                afr[rt][ks] = a;
            }
    } else {
        uint4 raw[2][KS];
#pragma unroll
        for (int rt = 0; rt < 2; rt++) {
            int arow = base + (wave * 2 + rt) * 16 + lrow;
            bool rok = arow < N;
#pragma unroll
            for (int ks = 0; ks < KS; ks++) {
                raw[rt][ks] = make_uint4(0u, 0u, 0u, 0u);
                if (rok) raw[rt][ks] = *(const uint4*)((const ushort*)Ain +
                                                       (size_t)arow * KD + ks * 32 + kg * 8);
            }
        }
#pragma unroll
        for (int rt = 0; rt < 2; rt++)
#pragma unroll
            for (int ks = 0; ks < KS; ks++) {
                int k0 = ks * 32 + kg * 8;
                unsigned int w[4] = {raw[rt][ks].x, raw[rt][ks].y, raw[rt][ks].z, raw[rt][ks].w};
                bf16x8 a;
#pragma unroll
                for (int p = 0; p < 4; p++) {
                    float f0 = us2f((ushort)(w[p] & 0xffffu));
                    float f1 = us2f((ushort)(w[p] >> 16));
                    f0 = fmaxf(f0 * faf[k0 + 2 * p][0] + faf[k0 + 2 * p][1], 0.f);
                    f1 = fmaxf(f1 * faf[k0 + 2 * p + 1][0] + faf[k0 + 2 * p + 1][1], 0.f);
                    a[2 * p] = (short)f2us(f0);
                    a[2 * p + 1] = (short)f2us(f1);
                }
                afr[rt][ks] = a;
            }
    }

#pragma unroll
    for (int rt = 0; rt < 2; rt++) {
        int tidx = wave * 2 + rt;
#pragma unroll
        for (int t = 0; t < NT; t++) {
            f32x4 acc = {0.f, 0.f, 0.f, 0.f};
#pragma unroll
            for (int ks = 0; ks < KS; ks++)
                acc = __builtin_amdgcn_mfma_f32_16x16x32_bf16(afr[rt][ks], wfr[t][ks], acc, 0, 0, 0);
            int colw = t * 16 + lrow;
#pragma unroll
            for (int r = 0; r < 4; r++) {
                int orow = base + tidx * 16 + kg * 4 + r;
                float v = acc[r] + bv[t];
                if (orow < N) {
                    if (MODE == 0) ((ushort*)outp)[(size_t)orow * ND + colw] = f2us(v);
                    else ((float*)outp)[(size_t)orow * ND + colw] = v;
                    ls[t] += v; lq[t] += v * v;
                }
            }
        }
    }

#pragma unroll
    for (int t = 0; t < NT; t++) {
        float a = ls[t], bq = lq[t];
        a += __shfl_xor(a, 16, 64); a += __shfl_xor(a, 32, 64);
        bq += __shfl_xor(bq, 16, 64); bq += __shfl_xor(bq, 32, 64);
        if (kg == 0) {
            atomicAdd(&ssum[t * 16 + lrow], a);
            atomicAdd(&sssq[t * 16 + lrow], bq);
        }
    }
    __syncthreads();
    if (tid < ND) {
        atomicAdd(&s_sum[tid], ssum[tid]);
        atomicAdd(&s_ssq[tid], sssq[tid]);
    }
}

// ---------------- final: out = relu(x0 + BN(y)) + eps (BN affine from stats) ----------------
__global__ void final_k(const float4* __restrict__ x0, const float4* __restrict__ y,
                        const float* __restrict__ sum, const float* __restrict__ ssq,
                        const float* __restrict__ g, const float* __restrict__ b,
                        float invN, float4* __restrict__ outp, int total4) {
    int i = blockIdx.x * 256 + threadIdx.x;
    if (i >= total4) return;
    int c0 = (i * 4) & 63;
    float4 yv = y[i], xv = x0[i];
    float yy[4] = {yv.x, yv.y, yv.z, yv.w};
    float xx[4] = {xv.x, xv.y, xv.z, xv.w};
    float oo[4];
#pragma unroll
    for (int j = 0; j < 4; j++) {
        float a, cc;
        bnaff(sum, ssq, g, b, invN, c0 + j, a, cc);
        oo[j] = fmaxf(xx[j] + yy[j] * a + cc, 0.f) + FEPS;
    }
    float4 o = make_float4(oo[0], oo[1], oo[2], oo[3]);
    outp[i] = o;
}

extern "C" void kernel_launch(void* const* d_in, const int* in_sizes, int n_in,
                              void* d_out, int out_size, void* d_ws, size_t ws_size,
                              hipStream_t stream) {
    const float* x0 = (const float*)d_in[0];
    const int* ei = (const int*)d_in[1];
    const float* t = (const float*)d_in[2];
    const float* scale = (const float*)d_in[3];
    const float* W1 = (const float*)d_in[4];
    const float* b1 = (const float*)d_in[5];
    const float* g1 = (const float*)d_in[6];
    const float* be1 = (const float*)d_in[7];
    const float* W2 = (const float*)d_in[8];
    const float* b2 = (const float*)d_in[9];
    const float* bn_g = (const float*)d_in[10];
    const float* bn_b = (const float*)d_in[11];

    const int N = in_sizes[0] / C;
    const int E = in_sizes[1] / 2;
    const int* src = ei;
    const int* dst = ei + E;
    const int NB = (N + BSZ - 1) >> BSH;   // 196 buckets (<=256)

    char* ws = (char*)d_ws;
    size_t cur = 0;
    auto alloc = [&](size_t bytes) -> char* {
        char* p = ws + cur;
        cur = (cur + bytes + 255) & ~(size_t)255;
        return p;
    };
    int* bucket_cnt = (int*)alloc(256 * 4);
    float* stats = (float*)alloc(768 * 4);          // [layer][sum1 128|ssq1 128|sum2 64|ssq2 64]
    size_t zbytes = cur;                            // zero only atomic targets
    int* bucket_off = (int*)alloc(257 * 4);
    int* bucket_fill = (int*)alloc(256 * 4);
    int* row_start = (int*)alloc(((size_t)N + 1) * 4);
    int* col = (int*)alloc((size_t)E * 4);
    ushort* marr = (ushort*)alloc((size_t)N * C * 2);    // bf16 messages
    ushort* wt1 = (ushort*)alloc(2 * H * C * 2);         // Wt1[2][128cols][64k] bf16
    ushort* wt2 = (ushort*)alloc(2 * C * H * 2);         // Wt2[2][64cols][128k] bf16
    float* bout = (float*)alloc((size_t)N * C * 4);
    ushort* bh = (ushort*)alloc((size_t)N * H * 2);      // h as bf16
    float* by = (float*)alloc((size_t)N * C * 4);
    // bpak aliases bh: CSR build finishes before first mlpm writes bh (E*4 <= N*H*2)
    unsigned int* bpak = (unsigned int*)bh;

    hipMemsetAsync(d_ws, 0, zbytes, stream);

    // weight pre-transpose (once)
    wprep_k<<<128, 256, 0, stream>>>(W1, W2, wt1, wt2);

    // CSR build (bucketed, packed scatter)
    int nbE = (E + EPB - 1) / EPB;
    bhist_k<<<nbE, 256, 0, stream>>>(dst, bucket_cnt, E, NB);
    bscan_k<<<1, 256, 0, stream>>>(bucket_cnt, bucket_off, bucket_fill, row_start, NB, N, E);
    bscat_k<<<nbE, 256, 0, stream>>>(src, dst, bucket_fill, bpak, E);
    bfine_k<<<NB, 512, 0, stream>>>(bucket_off, bpak, row_start, col, N);

    float* sum1_0 = stats + 0;   float* ssq1_0 = stats + 128;
    float* sum2_0 = stats + 256; float* ssq2_0 = stats + 320;
    float* sum1_1 = stats + 384; float* ssq1_1 = stats + 512;
    float* sum2_1 = stats + 640; float* ssq2_1 = stats + 704;

    const float invN = 1.0f / (float)N;
    int nbN16 = (N + 15) / 16;            // agg: 16 nodes per block
    int nbT2 = (N + 127) / 128;           // GEMM row tiles (BM=128)
    int nbP = (N * C / 4 + 255) / 256;    // prep/final

    // ---- layer 0 ----
    prep_k<0><<<nbP, 256, 0, stream>>>(x0, nullptr, nullptr, nullptr, nullptr, 0.f,
                                       marr, N * C / 4);
    agg_k<0><<<nbN16, 256, 0, stream>>>(x0, nullptr, nullptr, nullptr, nullptr, 0.f,
                                        (const uint2*)marr, row_start, col,
                                        t, scale, 0, bout, N);
    mlpm_k<C, H, 0><<<nbT2, 256, 0, stream>>>(bout, nullptr, nullptr, nullptr, nullptr, 0.f,
                                              wt1, b1, bh, sum1_0, ssq1_0, N);
    mlpm_k<H, C, 1><<<nbT2, 256, 0, stream>>>(bh, sum1_0, ssq1_0, g1, be1, invN,
                                              wt2, b2, by, sum2_0, ssq2_0, N);

    // ---- layer 1 ----
    prep_k<1><<<nbP, 256, 0, stream>>>(by, sum2_0, ssq2_0, bn_g, bn_b, invN,
                                       marr, N * C / 4);
    agg_k<1><<<nbN16, 256, 0, stream>>>(by, sum2_0, ssq2_0, bn_g, bn_b, invN,
                                        (const uint2*)marr, row_start, col,
                                        t, scale, 1, bout, N);
    mlpm_k<C, H, 0><<<nbT2, 256, 0, stream>>>(bout, nullptr, nullptr, nullptr, nullptr, 0.f,
                                              wt1 + H * C, b1 + H, bh, sum1_1, ssq1_1, N);
    mlpm_k<H, C, 1><<<nbT2, 256, 0, stream>>>(bh, sum1_1, ssq1_1, g1 + H, be1 + H, invN,
                                              wt2 + C * H, b2 + C, by, sum2_1, ssq2_1, N);

    // ---- residual + relu + eps (BN folded) ----
    final_k<<<nbP, 256, 0, stream>>>((const float4*)x0, (const float4*)by,
                                     sum2_1, ssq2_1, bn_g + C, bn_b + C, invN,
                                     (float4*)d_out, N * C / 4);
}